// Round 11
// baseline (118.762 us; speedup 1.0000x reference)
//
#include <hip/hip_runtime.h>
#include <hip/hip_fp16.h>

#define NQ 12
#define DEPTH 8
#define NCLASS 10
#define BATCH 4096
#define LSTRIDE 68   // LDS row stride in DWORDS (272 B; 16B-aligned rows; conflict-free, measured 0)

// ---------------------------------------------------------------------------
// R11: pair-split. One 128-thread block = 2 waves = 2 samples (half2-packed).
// Each wave holds HALF the 64x64-dword state: 32 dwords/lane.
//   Frame A: q0..5 <-> lane bits 5..0; q6 = wave bit w; q7..11 <-> j bits 4..0
//   Frame B: q6..11 <-> lane bits 5..0; q0 = wave bit w; q1..5  <-> j bits 4..0
// Per layer (4 barriers, single shared buffer):
//   W1(stage A) B R1(perm+transpose -> B; row = hfun(j)^(w*0x30), additive
//   +48/+16 per j-bit4; col = g(l)^(j odd ? 0x30 : 0)) ; shear q1..5 (reg),
//   q6 (lane^32 via v_permlane32_swap) B W2 B R2(transpose -> A) ; shear
//   q7..11 (reg), q0 (lane^32) B.
// Cross-wave shears avoided by doing q6 in frame B / q0 in frame A.
// Shears = tan-half-angle form; global cos product deferred to epilogue.
// ---------------------------------------------------------------------------

typedef unsigned int uint2v __attribute__((ext_vector_type(2)));

__device__ __forceinline__ uint32_t h2u(__half2 x) { return __builtin_bit_cast(uint32_t, x); }
__device__ __forceinline__ __half2 u2h(uint32_t x) { return __builtin_bit_cast(__half2, x); }

__device__ constexpr int hfun(int r) {  // src row for RT1 output reg r (CNOT index map)
    const int rb5 = (r >> 5) & 1, rb4 = (r >> 4) & 1, rb3 = (r >> 3) & 1;
    const int rb2 = (r >> 2) & 1, rb1 = (r >> 1) & 1, rb0 = r & 1;
    const int c0 = rb5;
    const int c1 = rb4 ^ rb5;
    const int c2 = rb3 ^ rb4;
    const int c3 = rb2 ^ rb3 ^ rb4;
    const int c4 = rb1 ^ rb2;
    const int c5 = rb0 ^ rb1 ^ rb2;
    return (c0 << 5) | (c1 << 4) | (c2 << 3) | (c3 << 2) | (c4 << 1) | c5;
}

// partner value across lane^32 (VALU path: permlane32_swap; fallback: shfl)
__device__ __forceinline__ uint32_t xchg32(uint32_t x, int lane) {
#if __has_builtin(__builtin_amdgcn_permlane32_swap)
    uint2v pr = __builtin_amdgcn_permlane32_swap(x, x, false, false);
    // new_dst = {x.lo, x.lo}, new_src = {x.hi, x.hi}; partner = l<32 ? src : dst
    return (lane < 32) ? pr.y : pr.x;
#else
    return (uint32_t)__shfl_xor((int)x, 32, 64);
#endif
}

// shear pair: a' = a - t*b ; b' = b + t*a  (neg folded into VOP3P modifier)
__device__ __forceinline__ void spair(uint32_t& a_, uint32_t& b_, __half2 T) {
    const __half2 a = u2h(a_), b = u2h(b_);
    a_ = h2u(__hfma2(__hneg2(T), b, a));
    b_ = h2u(__hfma2(T, a, b));
}

template <int M>
__device__ __forceinline__ void shear_reg(uint32_t (&v)[32], __half2 T) {
#pragma unroll
    for (int r = 0; r < 32; ++r) {
        if (r & M) continue;
        spair(v[r], v[r | M], T);
    }
}

__device__ __forceinline__ float wave_sum(float r) {
#pragma unroll
    for (int m = 0; m < 6; ++m) r += __shfl_xor(r, 1 << m, 64);
    return r;
}

__global__ __launch_bounds__(128) void vqc_kernel(const float* __restrict__ X,
                                                  const float* __restrict__ W,
                                                  float* __restrict__ out) {
    __shared__ __align__(16) uint32_t lds[64 * LSTRIDE];
    __shared__ float red[2][2][NCLASS];

    const int l  = threadIdx.x & 63;
    const int w  = threadIdx.x >> 6;           // wave id = split bit
    const int s0 = 2 * blockIdx.x, s1 = s0 + 1;

    // staging pointers (both RT writes share the same layout: row=lane, col=32w+j)
    uint32_t* wptr = &lds[l * LSTRIDE + 32 * w];
    const int G = l ^ (l >> 1) ^ ((l >> 2) & 5);       // RT1 src col (lane-local CNOTs folded)
    const int ro0 = w ? 48 * LSTRIDE : 0;              // row offset, j bit4 == 0
    const int ro1 = w ? 16 * LSTRIDE : 0;              // row offset, j bit4 == 1
    const uint32_t* r1_00 = &lds[G + ro0];             // j even, bit4=0
    const uint32_t* r1_10 = &lds[(G ^ 0x30) + ro0];    // j odd,  bit4=0  (CNOT(5,6) col flip)
    const uint32_t* r1_01 = &lds[G + ro1];             // j even, bit4=1
    const uint32_t* r1_11 = &lds[(G ^ 0x30) + ro1];    // j odd,  bit4=1
    const uint32_t* r2    = &lds[(32 * w) * LSTRIDE + l];

    // ---- data encoding: product state for both samples, frame A ----
    float cx0[NQ], sx0[NQ], cx1[NQ], sx1[NQ];
#pragma unroll
    for (int q = 0; q < NQ; ++q) {
        __sincosf(0.5f * X[s0 * NQ + q] + 0.78539816339744831f, &sx0[q], &cx0[q]);
        __sincosf(0.5f * X[s1 * NQ + q] + 0.78539816339744831f, &sx1[q], &cx1[q]);
    }
    float P0 = w ? sx0[6] : cx0[6];   // qubit-6 factor = wave bit
    float P1 = w ? sx1[6] : cx1[6];
#pragma unroll
    for (int q = 0; q < 6; ++q) {
        P0 *= ((l >> (5 - q)) & 1) ? sx0[q] : cx0[q];
        P1 *= ((l >> (5 - q)) & 1) ? sx1[q] : cx1[q];
    }

    uint32_t v[32];
    v[0] = h2u(__floats2half2_rn(P0 * cx0[11], P1 * cx1[11]));
    v[1] = h2u(__floats2half2_rn(P0 * sx0[11], P1 * sx1[11]));
#pragma unroll
    for (int lvl = 1; lvl < 5; ++lvl) {
        const int q = 11 - lvl;
        const __half2 SX = __floats2half2_rn(sx0[q], sx1[q]);
        const __half2 CX = __floats2half2_rn(cx0[q], cx1[q]);
#pragma unroll
        for (int j = 0; j < 16; ++j) {
            if (j >= (1 << lvl)) continue;
            v[j + (1 << lvl)] = h2u(__hmul2(u2h(v[j]), SX));
            v[j]              = h2u(__hmul2(u2h(v[j]), CX));
        }
    }

    float Call = 1.0f;   // product of cos(w/2) over all gates (deferred scale)

    // ---- variational layers ----
#pragma unroll 1
    for (int k = 0; k < DEPTH; ++k) {
        __half2 T[NQ];
#pragma unroll
        for (int q = 0; q < NQ; ++q) {
            float cw, sw;
            __sincosf(0.5f * W[k * NQ + q], &sw, &cw);
            Call *= cw;
            const float t = sw / cw;
            T[q] = __floats2half2_rn(t, t);
        }

        // W1: stage frame-A state
#pragma unroll
        for (int t8 = 0; t8 < 8; ++t8)
            *(uint4*)&wptr[4 * t8] = make_uint4(v[4 * t8], v[4 * t8 + 1],
                                                v[4 * t8 + 2], v[4 * t8 + 3]);
        __syncthreads();

        // R1: (transpose ∘ CNOT_odd ∘ CNOT_even) -> frame B
#pragma unroll
        for (int j = 0; j < 32; ++j) {
            const uint32_t* base = (j & 16) ? ((j & 1) ? r1_11 : r1_01)
                                            : ((j & 1) ? r1_10 : r1_00);
            v[j] = base[hfun(j) * LSTRIDE];
        }

        // frame-B shears: q1..q5 (reg-local), q6 (lane^32)
        shear_reg<16>(v, T[1]);
        shear_reg<8>(v, T[2]);
        shear_reg<4>(v, T[3]);
        shear_reg<2>(v, T[4]);
        shear_reg<1>(v, T[5]);
        {
            const __half2 tS = (l < 32) ? __hneg2(T[6]) : T[6];
#pragma unroll
            for (int j = 0; j < 32; ++j) {
                const uint32_t p = xchg32(v[j], l);
                v[j] = h2u(__hfma2(tS, u2h(p), u2h(v[j])));
            }
        }
        __syncthreads();   // all R1 reads done before buffer rewrite

        // W2: stage frame-B state
#pragma unroll
        for (int t8 = 0; t8 < 8; ++t8)
            *(uint4*)&wptr[4 * t8] = make_uint4(v[4 * t8], v[4 * t8 + 1],
                                                v[4 * t8 + 2], v[4 * t8 + 3]);
        __syncthreads();

        // R2: plain transpose -> frame A
#pragma unroll
        for (int j = 0; j < 32; ++j)
            v[j] = r2[j * LSTRIDE];

        // frame-A shears: q7..q11 (reg-local), q0 (lane^32)
        shear_reg<16>(v, T[7]);
        shear_reg<8>(v, T[8]);
        shear_reg<4>(v, T[9]);
        shear_reg<2>(v, T[10]);
        shear_reg<1>(v, T[11]);
        {
            const __half2 tS = (l < 32) ? __hneg2(T[0]) : T[0];
#pragma unroll
            for (int j = 0; j < 32; ++j) {
                const uint32_t p = xchg32(v[j], l);
                v[j] = h2u(__hfma2(tS, u2h(p), u2h(v[j])));
            }
        }
        __syncthreads();   // all R2 reads done before next layer's W1
    }

    const float C2 = Call * Call;   // deferred |amplitude|^2 scale

    // ---- measurement (fp32), frame A: q0..5 lane bits, q6 = w, q7..9 = j bits 4..2 ----
    float c20[8], c21[8];
#pragma unroll
    for (int m = 0; m < 8; ++m) {
        float a0 = 0.0f, a1 = 0.0f;
#pragma unroll
        for (int i = 0; i < 4; ++i) {
            const float2 f = __half22float2(u2h(v[4 * m + i]));
            a0 += f.x * f.x;
            a1 += f.y * f.y;
        }
        c20[m] = a0;
        c21[m] = a1;
    }

    float S0 = 0.0f, S1 = 0.0f;
#pragma unroll
    for (int m = 0; m < 8; ++m) { S0 += c20[m]; S1 += c21[m]; }
    S0 *= C2; S1 *= C2;

    float T0[3], T1[3];   // signed on m bit t: t=0->q9, 1->q8, 2->q7
#pragma unroll
    for (int t = 0; t < 3; ++t) {
        float a0 = 0.0f, a1 = 0.0f;
#pragma unroll
        for (int m = 0; m < 8; ++m) {
            const float sgn = ((m >> t) & 1) ? -1.0f : 1.0f;
            a0 += sgn * c20[m];
            a1 += sgn * c21[m];
        }
        T0[t] = a0 * C2;
        T1[t] = a1 * C2;
    }

    float p0[NCLASS], p1[NCLASS];
#pragma unroll
    for (int p = 0; p < 6; ++p) {   // qubit p on lane bit (5-p)
        const float sgn = ((l >> (5 - p)) & 1) ? -1.0f : 1.0f;
        p0[p] = wave_sum(sgn * S0);
        p1[p] = wave_sum(sgn * S1);
    }
    {
        const float ws = w ? -1.0f : 1.0f;   // qubit 6 = wave bit
        p0[6] = ws * wave_sum(S0);
        p1[6] = ws * wave_sum(S1);
    }
#pragma unroll
    for (int p = 7; p < 10; ++p) {  // qubit p on j bit (11-p) -> T[9-p... p=7->T[2]]
        p0[p] = wave_sum(T0[9 - p]);
        p1[p] = wave_sum(T1[9 - p]);
    }

    if (l == 0) {
#pragma unroll
        for (int p = 0; p < NCLASS; ++p) {
            red[w][0][p] = p0[p];
            red[w][1][p] = p1[p];
        }
    }
    __syncthreads();
    if (threadIdx.x < 2 * NCLASS) {
        const int s = threadIdx.x / NCLASS, p = threadIdx.x % NCLASS;
        out[(s0 + s) * NCLASS + p] = red[0][s][p] + red[1][s][p];
    }
}

extern "C" void kernel_launch(void* const* d_in, const int* in_sizes, int n_in,
                              void* d_out, int out_size, void* d_ws, size_t ws_size,
                              hipStream_t stream) {
    const float* X = (const float*)d_in[0];
    const float* W = (const float*)d_in[1];
    float* out     = (float*)d_out;
    (void)in_sizes; (void)n_in; (void)out_size; (void)d_ws; (void)ws_size;

    dim3 grid(BATCH / 2);   // 2 samples per block (2 waves, half state each)
    dim3 block(128);
    hipLaunchKernelGGL(vqc_kernel, grid, block, 0, stream, X, W, out);
}

// Round 12
// 97.281 us; speedup vs baseline: 1.2208x; 1.2208x over previous
//
#include <hip/hip_runtime.h>
#include <hip/hip_fp16.h>

#define NQ 12
#define DEPTH 8
#define NCLASS 10
#define BATCH 4096
#define LSTRIDE 68   // LDS row stride in DWORDS (272 B; 16B-aligned rows; conflict-free, measured 0)
#define WPB 2        // waves per block; 2 samples/wave; LDS = 2*64*68*4 = 34816 B

// ---------------------------------------------------------------------------
// One wave per TWO samples; amplitude pair packed as __half2 in v[64] dwords.
// Frame A: qubit q in 0..5  <-> lane bit (5-q);  q in 6..11 <-> reg bit (11-q)
// Frame B: qubit q in 0..5  <-> reg  bit (5-q);  q in 6..11 <-> lane bit (11-q)
// R12 = R8 with shear CONSUMPTION ORDER matched to read-arrival order:
//   reads r=0..63 (in-order lgkmcnt); shear masks {16,8,4,2,1} on v[0..31]
//   (ready after first 32 reads; RT1 rows for r<32 are a prefix since
//   hfun(r)<32 iff r<32), then same on v[32..63], then mask-32 last.
//   (R8 did mask-32 first -> full 64-read drain before any shear.)
// Plus a one-time s_sleep stagger for wave 1 to anti-phase the two waves'
// DS bursts on the shared LDS pipe.
// Shears = tan-half-angle; global cos product deferred to epilogue.
// All DS intra-wave (private region per wave, DS in-order) -> no barriers.
// ---------------------------------------------------------------------------

__device__ __forceinline__ uint32_t h2u(__half2 x) { return __builtin_bit_cast(uint32_t, x); }
__device__ __forceinline__ __half2 u2h(uint32_t x) { return __builtin_bit_cast(__half2, x); }

__device__ constexpr int hfun(int r) {  // src row (old lane) for RT1 output reg r
    const int rb5 = (r >> 5) & 1, rb4 = (r >> 4) & 1, rb3 = (r >> 3) & 1;
    const int rb2 = (r >> 2) & 1, rb1 = (r >> 1) & 1, rb0 = r & 1;
    const int c0 = rb5;
    const int c1 = rb4 ^ rb5;
    const int c2 = rb3 ^ rb4;
    const int c3 = rb2 ^ rb3 ^ rb4;
    const int c4 = rb1 ^ rb2;
    const int c5 = rb0 ^ rb1 ^ rb2;
    return (c0 << 5) | (c1 << 4) | (c2 << 3) | (c3 << 2) | (c4 << 1) | c5;
}

// shear pair: a' = a - t*b ; b' = b + t*a  (tan half-angle form)
__device__ __forceinline__ void spair(uint32_t& a_, uint32_t& b_, __half2 Tp, __half2 Tn) {
    const __half2 a = u2h(a_), b = u2h(b_);
    a_ = h2u(__hfma2(Tn, b, a));
    b_ = h2u(__hfma2(Tp, a, b));
}

// shear masks {16,8,4,2,1} (qubits in order) applied to a 32-reg half
__device__ __forceinline__ void shear_half(uint32_t* v, const __half2* Tp, const __half2* Tn) {
#pragma unroll
    for (int m = 0; m < 5; ++m) {
        const int M = 16 >> m;
#pragma unroll
        for (int r = 0; r < 32; ++r) {
            if (r & M) continue;
            spair(v[r], v[r | M], Tp[m], Tn[m]);
        }
    }
}

__global__ __launch_bounds__(WPB * 64) void vqc_kernel(const float* __restrict__ X,
                                                       const float* __restrict__ W,
                                                       float* __restrict__ out) {
    __shared__ __align__(16) uint32_t lds[WPB * 64 * LSTRIDE];

    const int lane = threadIdx.x & 63;
    const int wid  = threadIdx.x >> 6;
    const int gw   = blockIdx.x * WPB + wid;   // global wave id
    const int s0   = 2 * gw, s1 = s0 + 1;      // the two samples
    const int l    = lane;

    uint32_t* Wb   = &lds[wid * 64 * LSTRIDE];
    uint32_t* wrow = &Wb[l * LSTRIDE];                 // staging write base (16B aligned)
    const int G = l ^ (l >> 1) ^ ((l >> 2) & 5);       // RT1 src col (lane-local CNOTs folded)
    const uint32_t* colA = &Wb[G];                     // r even (q5=0)
    const uint32_t* colB = &Wb[G ^ 0x30];              // r odd  (q5=1): CNOT(5,6) col flip
    const uint32_t* rT2  = &Wb[l];                     // RT2 read base

    // ---- data encoding: product state for both samples, frame A ----
    float cx0[NQ], sx0[NQ], cx1[NQ], sx1[NQ];
#pragma unroll
    for (int q = 0; q < NQ; ++q) {
        __sincosf(0.5f * X[s0 * NQ + q] + 0.78539816339744831f, &sx0[q], &cx0[q]);
        __sincosf(0.5f * X[s1 * NQ + q] + 0.78539816339744831f, &sx1[q], &cx1[q]);
    }
    float P0 = 1.0f, P1 = 1.0f;
#pragma unroll
    for (int q = 0; q < 6; ++q) {
        P0 *= ((l >> (5 - q)) & 1) ? sx0[q] : cx0[q];
        P1 *= ((l >> (5 - q)) & 1) ? sx1[q] : cx1[q];
    }

    uint32_t v[64];
    v[0] = h2u(__floats2half2_rn(P0 * cx0[11], P1 * cx1[11]));
    v[1] = h2u(__floats2half2_rn(P0 * sx0[11], P1 * sx1[11]));
#pragma unroll
    for (int lvl = 1; lvl < 6; ++lvl) {
        const int q = 11 - lvl;
        const __half2 SX = __floats2half2_rn(sx0[q], sx1[q]);
        const __half2 CX = __floats2half2_rn(cx0[q], cx1[q]);
#pragma unroll
        for (int j = 0; j < (1 << 5); ++j) {
            if (j >= (1 << lvl)) continue;
            v[j + (1 << lvl)] = h2u(__hmul2(u2h(v[j]), SX));
            v[j]              = h2u(__hmul2(u2h(v[j]), CX));
        }
    }

    // desync the two waves' DS bursts (one-time, correctness-neutral)
    if (wid) __builtin_amdgcn_s_sleep(4);

    float Call = 1.0f;   // product of cos(w/2) over all gates (deferred scale)

    // ---- variational layers ----
#pragma unroll 1
    for (int k = 0; k < DEPTH; ++k) {
        __half2 Tp[NQ], Tn[NQ];
#pragma unroll
        for (int q = 0; q < NQ; ++q) {
            float cw, sw;
            __sincosf(0.5f * W[k * NQ + q], &sw, &cw);
            Call *= cw;
            const float t = sw / cw;
            Tp[q] = __floats2half2_rn(t, t);
            Tn[q] = __floats2half2_rn(-t, -t);
        }

        // ---- RT1 write: frame A rows, b128 ----
#pragma unroll
        for (int t = 0; t < 16; ++t)
            *(uint4*)&wrow[4 * t] = make_uint4(v[4 * t], v[4 * t + 1], v[4 * t + 2], v[4 * t + 3]);

        // ---- RT1 reads (r = 0..63; rows for r<32 are a prefix) ----
#pragma unroll
        for (int r = 0; r < 64; ++r)
            v[r] = ((r & 1) ? colB : colA)[hfun(r) * LSTRIDE];

        // ---- frame-B shears in read-arrival order: lower half, upper half, mask-32 ----
        shear_half(&v[0],  &Tp[1], &Tn[1]);   // qubits 1..5 on v[0..31]
        shear_half(&v[32], &Tp[1], &Tn[1]);   // qubits 1..5 on v[32..63]
#pragma unroll
        for (int r = 0; r < 32; ++r)          // qubit 0 (mask 32) last
            spair(v[r], v[r + 32], Tp[0], Tn[0]);

        // ---- RT2 write: frame B rows, b128 ----
#pragma unroll
        for (int t = 0; t < 16; ++t)
            *(uint4*)&wrow[4 * t] = make_uint4(v[4 * t], v[4 * t + 1], v[4 * t + 2], v[4 * t + 3]);

        // ---- RT2 reads (j = 0..63) ----
#pragma unroll
        for (int j = 0; j < 64; ++j)
            v[j] = rT2[j * LSTRIDE];

        // ---- frame-A shears in read-arrival order: lower half, upper half, mask-32 ----
        shear_half(&v[0],  &Tp[7], &Tn[7]);   // qubits 7..11 on v[0..31]
        shear_half(&v[32], &Tp[7], &Tn[7]);   // qubits 7..11 on v[32..63]
#pragma unroll
        for (int r = 0; r < 32; ++r)          // qubit 6 (mask 32) last
            spair(v[r], v[r + 32], Tp[6], Tn[6]);
    }

    const float C2 = (Call * Call);   // deferred |amplitude|^2 scale

    // ---- measurement (fp32): <Z_p> per sample, frame A ----
    float c20[16], c21[16];
#pragma unroll
    for (int m = 0; m < 16; ++m) {
        float a0 = 0.0f, a1 = 0.0f;
#pragma unroll
        for (int i = 0; i < 4; ++i) {
            const float2 f = __half22float2(u2h(v[4 * m + i]));
            a0 += f.x * f.x;
            a1 += f.y * f.y;
        }
        c20[m] = a0;
        c21[m] = a1;
    }

    float S0 = 0.0f, S1 = 0.0f;
#pragma unroll
    for (int m = 0; m < 16; ++m) { S0 += c20[m]; S1 += c21[m]; }
    S0 *= C2; S1 *= C2;

    float T0[4], T1[4];
#pragma unroll
    for (int t = 0; t < 4; ++t) {
        float a0 = 0.0f, a1 = 0.0f;
#pragma unroll
        for (int m = 0; m < 16; ++m) {
            const float sgn = ((m >> t) & 1) ? -1.0f : 1.0f;
            a0 += sgn * c20[m];
            a1 += sgn * c21[m];
        }
        T0[t] = a0 * C2;
        T1[t] = a1 * C2;
    }

    float o0[NCLASS], o1[NCLASS];
#pragma unroll
    for (int p = 0; p < 6; ++p) {   // qubit p on lane bit (5-p)
        const float sgn = ((l >> (5 - p)) & 1) ? -1.0f : 1.0f;
        float r0 = sgn * S0, r1 = sgn * S1;
#pragma unroll
        for (int m = 0; m < 6; ++m) { r0 += __shfl_xor(r0, 1 << m, 64); r1 += __shfl_xor(r1, 1 << m, 64); }
        o0[p] = r0; o1[p] = r1;
    }
#pragma unroll
    for (int p = 6; p < 10; ++p) {  // qubit p on reg bit (11-p) -> T[9-p]
        float r0 = T0[9 - p], r1 = T1[9 - p];
#pragma unroll
        for (int m = 0; m < 6; ++m) { r0 += __shfl_xor(r0, 1 << m, 64); r1 += __shfl_xor(r1, 1 << m, 64); }
        o0[p] = r0; o1[p] = r1;
    }

    if (lane == 0) {
#pragma unroll
        for (int p = 0; p < NCLASS; ++p) {
            out[s0 * NCLASS + p] = o0[p];
            out[s1 * NCLASS + p] = o1[p];
        }
    }
}

extern "C" void kernel_launch(void* const* d_in, const int* in_sizes, int n_in,
                              void* d_out, int out_size, void* d_ws, size_t ws_size,
                              hipStream_t stream) {
    const float* X = (const float*)d_in[0];
    const float* W = (const float*)d_in[1];
    float* out     = (float*)d_out;
    (void)in_sizes; (void)n_in; (void)out_size; (void)d_ws; (void)ws_size;

    dim3 grid(BATCH / (2 * WPB));   // 2 samples per wave, WPB waves per block
    dim3 block(WPB * 64);
    hipLaunchKernelGGL(vqc_kernel, grid, block, 0, stream, X, W, out);
}